// Round 8
// baseline (208.163 us; speedup 1.0000x reference)
//
#include <hip/hip_runtime.h>
#include <hip/hip_fp16.h>

// Problem constants (from reference):
//   x:    (B=2, C=8, F=80, N=128, N=128) fp32
//   quad: (H=512, W=1024) int32 in [0, F)
//   uv:   (H, W, 2) fp32 in [0, N-1)
//   out:  (B, C, H, W) fp32
#define BC   16                 // B*C
#define FD   80
#define ND   128
#define NN   (ND * ND)          // 16384
#define HW   (512 * 1024)       // 524288 = 2^19
#define HW_SHIFT 19
#define HALF_HW (HW / 2)

#define YH_BYTES ((size_t)FD * NN * BC * sizeof(__half))   // 41,943,040

// Native clang vector type — legal for __builtin_nontemporal_load/store.
typedef unsigned int v4u __attribute__((ext_vector_type(4)));

// ---------------------------------------------------------------------------
// Kernel 1 (repack v4): x[bc][f][v][u] fp32 -> y[f][v][u][bc] fp16.
// One thread per 4 texels: 16 float4 loads (1 KB/wave-instr, coalesced) +
// 8 contiguous 16B stores. No LDS, single copy.
// ---------------------------------------------------------------------------
__global__ __launch_bounds__(256)
void repack_kernel(const float* __restrict__ x, __half* __restrict__ y)
{
    const int t  = blockIdx.x * 256 + threadIdx.x;   // 0 .. FD*ND*ND/4 - 1
    const int u4 = t & 31;                           // float4 index along u
    const int fv = t >> 5;                           // f*128 + v
    const int f  = fv >> 7;
    const int v  = fv & (ND - 1);

    // 16 coalesced float4 loads (within-wave lanes are consecutive u4
    // -> 1 KB contiguous per instruction).
    float4 g[BC];
#pragma unroll
    for (int c = 0; c < BC; ++c)
        g[c] = *(const float4*)(x + (((size_t)c * FD + f) * ND + v) * ND + u4 * 4);

    // Transpose in registers: 4 texels x 16 channels, pack to fp16.
    __half* yp = y + ((size_t)fv * ND + (size_t)u4 * 4) * BC;
#pragma unroll
    for (int k = 0; k < 4; ++k) {
        unsigned hp[8];
#pragma unroll
        for (int j = 0; j < 8; ++j) {
            const float a = ((const float*)&g[2 * j    ])[k];
            const float b = ((const float*)&g[2 * j + 1])[k];
            const __half2 h = __floats2half2_rn(a, b);
            hp[j] = *(const unsigned*)&h;
        }
        v4u lo = { hp[0], hp[1], hp[2], hp[3] };
        v4u hi = { hp[4], hp[5], hp[6], hp[7] };
        *(v4u*)(yp + k * BC)     = lo;
        *(v4u*)(yp + k * BC + 8) = hi;
    }
}

// ---------------------------------------------------------------------------
// Kernel 2 (gather v4): one thread per TWO pixels (pix, pix+HW/2).
// 16 nontemporal 16B texel loads in flight before any waitcnt; weights
// computed once per pixel; 32 coalesced nontemporal stores.
// ---------------------------------------------------------------------------
__device__ inline void acc8(float* o, v4u t, float w)
{
#pragma unroll
    for (int j = 0; j < 4; ++j) {
        const unsigned w32 = t[j];
        const float2 fp = __half22float2(*(const __half2*)&w32);
        o[2 * j + 0] += fp.x * w;
        o[2 * j + 1] += fp.y * w;
    }
}

__device__ inline size_t texel_base(int f, const float2 t,
                                    float& du, float& dv)
{
    int u0 = (int)floorf(t.x);
    int v0 = (int)floorf(t.y);
    u0 = min(max(u0, 0), ND - 2);
    v0 = min(max(v0, 0), ND - 2);
    du = t.x - (float)u0;
    dv = t.y - (float)v0;
    return (((size_t)f * ND + v0) * ND + u0) * BC;
}

__global__ __launch_bounds__(256, 4)
void gather_kernel(const __half* __restrict__ y,
                   const int*    __restrict__ quad,
                   const float2* __restrict__ uv2,
                   float* __restrict__ out)
{
    const int p0 = blockIdx.x * 256 + threadIdx.x;   // 0 .. HALF_HW-1
    const int p1 = p0 + HALF_HW;

    const float2 t0 = uv2[p0];
    const float2 t1 = uv2[p1];
    const int    f0 = quad[p0];
    const int    f1 = quad[p1];

    float du0, dv0, du1, dv1;
    const size_t base0 = texel_base(f0, t0, du0, dv0);
    const size_t base1 = texel_base(f1, t1, du1, dv1);

    const v4u* r0a = (const v4u*)(y + base0);                    // pix0 row v0
    const v4u* r0b = (const v4u*)(y + base0 + (size_t)ND * BC);  // pix0 row v0+1
    const v4u* r1a = (const v4u*)(y + base1);                    // pix1 row v0
    const v4u* r1b = (const v4u*)(y + base1 + (size_t)ND * BC);  // pix1 row v0+1

    // 16 nontemporal 16B loads, all issued before first use.
    const v4u a0 = __builtin_nontemporal_load(r0a + 0);
    const v4u a1 = __builtin_nontemporal_load(r0a + 1);
    const v4u b0 = __builtin_nontemporal_load(r0a + 2);
    const v4u b1 = __builtin_nontemporal_load(r0a + 3);
    const v4u c0 = __builtin_nontemporal_load(r0b + 0);
    const v4u c1 = __builtin_nontemporal_load(r0b + 1);
    const v4u d0 = __builtin_nontemporal_load(r0b + 2);
    const v4u d1 = __builtin_nontemporal_load(r0b + 3);
    const v4u e0 = __builtin_nontemporal_load(r1a + 0);
    const v4u e1 = __builtin_nontemporal_load(r1a + 1);
    const v4u g0 = __builtin_nontemporal_load(r1a + 2);
    const v4u g1 = __builtin_nontemporal_load(r1a + 3);
    const v4u h0 = __builtin_nontemporal_load(r1b + 0);
    const v4u h1 = __builtin_nontemporal_load(r1b + 1);
    const v4u i0 = __builtin_nontemporal_load(r1b + 2);
    const v4u i1 = __builtin_nontemporal_load(r1b + 3);

    const float w00a = (1.0f - du0) * (1.0f - dv0);
    const float w01a = du0 * (1.0f - dv0);
    const float w10a = (1.0f - du0) * dv0;
    const float w11a = du0 * dv0;
    const float w00b = (1.0f - du1) * (1.0f - dv1);
    const float w01b = du1 * (1.0f - dv1);
    const float w10b = (1.0f - du1) * dv1;
    const float w11b = du1 * dv1;

    float o0[BC], o1[BC];
#pragma unroll
    for (int c = 0; c < BC; ++c) { o0[c] = 0.0f; o1[c] = 0.0f; }

    acc8(o0,     a0, w00a); acc8(o0 + 8, a1, w00a);
    acc8(o0,     b0, w01a); acc8(o0 + 8, b1, w01a);
    acc8(o0,     c0, w10a); acc8(o0 + 8, c1, w10a);
    acc8(o0,     d0, w11a); acc8(o0 + 8, d1, w11a);
    acc8(o1,     e0, w00b); acc8(o1 + 8, e1, w00b);
    acc8(o1,     g0, w01b); acc8(o1 + 8, g1, w01b);
    acc8(o1,     h0, w10b); acc8(o1 + 8, h1, w10b);
    acc8(o1,     i0, w11b); acc8(o1 + 8, i1, w11b);

#pragma unroll
    for (int c = 0; c < BC; ++c) {
        __builtin_nontemporal_store(o0[c], &out[(size_t)c * HW + p0]);
        __builtin_nontemporal_store(o1[c], &out[(size_t)c * HW + p1]);
    }
}

// ---------------------------------------------------------------------------
// Fallback: used only if ws_size can't hold the repacked texture.
// ---------------------------------------------------------------------------
__global__ __launch_bounds__(256)
void resample_fallback_kernel(const float* __restrict__ x,
                              const int*   __restrict__ quad,
                              const float2* __restrict__ uv2,
                              float* __restrict__ out)
{
    const int gid = blockIdx.x * 256 + threadIdx.x;
    const int pix = gid & (HW - 1);
    const int bc  = gid >> HW_SHIFT;

    const float2 t = uv2[pix];
    const int    f = quad[pix];

    const float u = t.x;
    const float v = t.y;

    int u0 = (int)floorf(u);
    int v0 = (int)floorf(v);
    u0 = min(max(u0, 0), ND - 2);
    v0 = min(max(v0, 0), ND - 2);

    const float du = u - (float)u0;
    const float dv = v - (float)v0;

    const float w00 = (1.0f - du) * (1.0f - dv);
    const float w01 = du * (1.0f - dv);
    const float w10 = (1.0f - du) * dv;
    const float w11 = du * dv;

    const float* p = x + ((size_t)bc * FD + (size_t)f) * NN + v0 * ND + u0;
    out[gid] = p[0] * w00 + p[1] * w01 + p[ND] * w10 + p[ND + 1] * w11;
}

extern "C" void kernel_launch(void* const* d_in, const int* in_sizes, int n_in,
                              void* d_out, int out_size, void* d_ws, size_t ws_size,
                              hipStream_t stream)
{
    const float*  x    = (const float*)d_in[0];
    const int*    quad = (const int*)d_in[1];
    const float2* uv2  = (const float2*)d_in[2];
    float*        out  = (float*)d_out;

    if (ws_size >= YH_BYTES) {
        __half* y = (__half*)d_ws;
        const int rp_threads = FD * ND * ND / 4;                 // 327,680
        repack_kernel<<<rp_threads / 256, 256, 0, stream>>>(x, y);   // 1280 blocks
        gather_kernel<<<HALF_HW / 256, 256, 0, stream>>>(y, quad, uv2, out); // 1024 blocks
    } else {
        const int total = BC * HW;
        resample_fallback_kernel<<<total / 256, 256, 0, stream>>>(x, quad, uv2, out);
    }
}